// Round 4
// baseline (745.135 us; speedup 1.0000x reference)
//
#include <hip/hip_runtime.h>
#include <hip/hip_bf16.h>

#define N_NODES 170000
#define N_EDGES 1200000

// ---- coarse/fine counting sort geometry ----
#define AITEMS 2048              // edges per coarse block
#define NB_A   586               // ceil(E / AITEMS)
#define NCB    333               // coarse buckets = ceil(N / 512), key = dst>>9
#define SCAN_A_N      (NCB * NB_A)        // 195138 counters
#define SCAN_A_BLOCKS 191                 // ceil(SCAN_A_N / 1024)
#define SCAN_A_PAD    (SCAN_A_BLOCKS * 1024)
#define HISTA_PAD     195140              // SCAN_A_N padded to 16B

// ---- deg_out chunked histogram geometry ----
#define DCH    16128             // nodes per LDS chunk (63KB of u32 counters)
#define NCHUNK 11                // ceil(N / DCH)
#define NSLICE 16                // edge slices (E/NSLICE = 75000 exactly)

typedef short bf16x8 __attribute__((ext_vector_type(8)));
typedef float f32x4 __attribute__((ext_vector_type(4)));

__device__ __forceinline__ void bf_split(float v, __hip_bfloat16& h, __hip_bfloat16& l)
{
    h = __float2bfloat16(v);
    l = __float2bfloat16(v - __bfloat162float(h));
}

// =====================================================================
// CSR build, zero global atomics.
// Round-2 lesson: global atomics execute at the memory-side coherence
// point REGARDLESS of scope (workgroup-scope showed identical 32B/atomic
// WRITE_SIZE). So the build is restructured as a deterministic two-phase
// counting sort using only LDS atomics + exclusively-owned global slots.
// =====================================================================

// ---- coarse histogram: per-block 333 counters of dst>>9, digit-major out ----
__global__ __launch_bounds__(256) void coarse_hist_kernel(
    const int* __restrict__ dst, int* __restrict__ histA, int nedges)
{
    __shared__ int h[NCB];
    int t = threadIdx.x;
    for (int j = t; j < NCB; j += 256) h[j] = 0;
    __syncthreads();
    int base = blockIdx.x * AITEMS;
    #pragma unroll
    for (int j = 0; j < AITEMS / 256; j++) {
        int i = base + j * 256 + t;
        if (i < nedges) atomicAdd(&h[dst[i] >> 9], 1);   // LDS atomic
    }
    __syncthreads();
    for (int j = t; j < NCB; j += 256)
        histA[j * NB_A + blockIdx.x] = h[j];
}

// ---- 3-phase exclusive scan (generic, reused for histA) ----
__global__ __launch_bounds__(256) void scan1_kernel(
    const int* __restrict__ in, int* __restrict__ partial,
    int* __restrict__ blockSums, int n)
{
    __shared__ int sdata[256];
    int t = threadIdx.x;
    int base = blockIdx.x * 1024 + t * 4;
    int4 v = make_int4(0, 0, 0, 0);
    if (base + 3 < n) v = *(const int4*)&in[base];
    else {
        if (base + 0 < n) v.x = in[base + 0];
        if (base + 1 < n) v.y = in[base + 1];
        if (base + 2 < n) v.z = in[base + 2];
        if (base + 3 < n) v.w = in[base + 3];
    }
    int tsum = v.x + v.y + v.z + v.w;
    sdata[t] = tsum;
    __syncthreads();
    for (int off = 1; off < 256; off <<= 1) {
        int add = 0;
        if (t >= off) add = sdata[t - off];
        __syncthreads();
        if (t >= off) sdata[t] += add;
        __syncthreads();
    }
    int excl = sdata[t] - tsum;
    int4 o;
    o.x = excl;
    o.y = o.x + v.x;
    o.z = o.y + v.y;
    o.w = o.z + v.z;
    *(int4*)&partial[base] = o;
    if (t == 255) blockSums[blockIdx.x] = sdata[255];
}

__global__ __launch_bounds__(256) void scan2_kernel(int* __restrict__ blockSums, int nb)
{
    __shared__ int sdata[256];
    int t = threadIdx.x;
    int val = (t < nb) ? blockSums[t] : 0;
    sdata[t] = val;
    __syncthreads();
    for (int off = 1; off < 256; off <<= 1) {
        int add = 0;
        if (t >= off) add = sdata[t - off];
        __syncthreads();
        if (t >= off) sdata[t] += add;
        __syncthreads();
    }
    if (t < nb) blockSums[t] = sdata[t] - val;   // exclusive
}

__global__ __launch_bounds__(256) void scan3_kernel(
    int* __restrict__ buf, const int* __restrict__ blockSums)
{
    int off = blockSums[blockIdx.x];
    int base = blockIdx.x * 1024 + threadIdx.x * 4;
    int4 v = *(const int4*)&buf[base];
    v.x += off; v.y += off; v.z += off; v.w += off;
    *(int4*)&buf[base] = v;
}

// ---- coarse scatter: (dst,src) pairs into coarse-bucket regions ----
// slot = scanA[digit][block] + LDS-rank. Slot sets are exclusive per
// (block,digit) so no global atomics; intra-set order is arbitrary (OK:
// aggregation is order-independent within a dst row).
__global__ __launch_bounds__(256) void coarse_scatter_kernel(
    const int* __restrict__ src, const int* __restrict__ dst,
    const int* __restrict__ scanA, int2* __restrict__ pairs, int nedges)
{
    __shared__ int base[NCB];
    __shared__ int cur[NCB];
    int t = threadIdx.x;
    for (int j = t; j < NCB; j += 256) {
        base[j] = scanA[j * NB_A + blockIdx.x];
        cur[j] = 0;
    }
    __syncthreads();
    int eb = blockIdx.x * AITEMS;
    #pragma unroll
    for (int j = 0; j < AITEMS / 256; j++) {
        int i = eb + j * 256 + t;
        if (i < nedges) {
            int d = dst[i];
            int cb = d >> 9;
            int r = atomicAdd(&cur[cb], 1);          // LDS atomic-return
            pairs[base[cb] + r] = make_int2(d, src[i]);
        }
    }
}

// ---- fine phase: one workgroup per coarse bucket ----
// LDS 512-hist of dst&511 == deg_in for the bucket's nodes -> norm_in +
// row_start written directly (bucket base + local exclusive scan); then
// re-read bucket, scatter src into csr via LDS cursors.
__global__ __launch_bounds__(256) void bucket_sort_kernel(
    const int2* __restrict__ pairs, const int* __restrict__ scanA,
    int* __restrict__ csr, int* __restrict__ row_start,
    float* __restrict__ norm_in, int nedges)
{
    __shared__ int hist[512];
    __shared__ int curs[512];
    __shared__ int sdata[256];
    int cb = blockIdx.x;
    int t = threadIdx.x;
    int beg = scanA[cb * NB_A];
    int end = (cb == NCB - 1) ? nedges : scanA[(cb + 1) * NB_A];

    hist[t] = 0; hist[t + 256] = 0;
    __syncthreads();
    for (int j = beg + t; j < end; j += 256)
        atomicAdd(&hist[pairs[j].x & 511], 1);
    __syncthreads();

    // exclusive scan of 512 counters (pairwise + Hillis-Steele over 256)
    int a = hist[2 * t], b = hist[2 * t + 1];
    sdata[t] = a + b;
    __syncthreads();
    for (int off = 1; off < 256; off <<= 1) {
        int add = 0;
        if (t >= off) add = sdata[t - off];
        __syncthreads();
        if (t >= off) sdata[t] += add;
        __syncthreads();
    }
    int epair = sdata[t] - (a + b);
    curs[2 * t]     = beg + epair;
    curs[2 * t + 1] = beg + epair + a;
    __syncthreads();

    int nodeBase = cb << 9;
    for (int s = t; s < 512; s += 256) {
        int v = nodeBase + s;
        if (v < N_NODES) {
            row_start[v] = curs[s];
            norm_in[v] = rsqrtf(fmaxf((float)hist[s], 1.0f));
        }
    }
    if (cb == NCB - 1 && t == 0) row_start[N_NODES] = nedges;
    __syncthreads();

    for (int j = beg + t; j < end; j += 256) {
        int2 p = pairs[j];
        int pos = atomicAdd(&curs[p.x & 511], 1);    // LDS atomic-return
        csr[pos] = p.y;
    }
}

// ---- deg_out: chunked-LDS replay histogram (counts only, no ranks) ----
// Block (chunk,slice): LDS-count src in [chunk*DCH, ...) over its edge
// slice, write exclusive region of partial[slice][...] with plain stores.
__global__ __launch_bounds__(256) void degout_hist_kernel(
    const int* __restrict__ src, int* __restrict__ partial, int nedges)
{
    __shared__ int h[DCH];
    int chunk = blockIdx.x / NSLICE;
    int slice = blockIdx.x % NSLICE;
    int lo = chunk * DCH;
    int t = threadIdx.x;
    for (int j = t; j < DCH; j += 256) h[j] = 0;
    __syncthreads();
    int s0 = slice * (N_EDGES / NSLICE);
    int s1 = s0 + (N_EDGES / NSLICE);
    for (int i = s0 + t; i < s1; i += 256) {
        unsigned v = (unsigned)(src[i] - lo);
        if (v < DCH) atomicAdd(&h[v], 1);            // LDS atomic
    }
    __syncthreads();
    int n = min(DCH, N_NODES - lo);
    for (int j = t; j < n; j += 256)
        partial[(size_t)slice * N_NODES + lo + j] = h[j];
}

__global__ __launch_bounds__(256) void degout_combine_kernel(
    const int* __restrict__ partial, float* __restrict__ norm_out, int n)
{
    int v = blockIdx.x * 256 + threadIdx.x;
    if (v >= n) return;
    int s = 0;
    #pragma unroll
    for (int x = 0; x < NSLICE; x++) s += partial[(size_t)x * N_NODES + v];
    norm_out[v] = rsqrtf(fmaxf((float)s, 1.0f));
}

// ---------------- fp32 -> bf16 row cast (feat) ----------------
__global__ __launch_bounds__(256) void f2bf_kernel(
    const float* __restrict__ in, __hip_bfloat16* __restrict__ outp, int n8)
{
    int i = blockIdx.x * 256 + threadIdx.x;
    if (i >= n8) return;
    float4 a = *(const float4*)&in[(size_t)i * 8];
    float4 b = *(const float4*)&in[(size_t)i * 8 + 4];
    float4 packed;
    __hip_bfloat162* p = (__hip_bfloat162*)&packed;
    p[0].x = __float2bfloat16(a.x); p[0].y = __float2bfloat16(a.y);
    p[1].x = __float2bfloat16(a.z); p[1].y = __float2bfloat16(a.w);
    p[2].x = __float2bfloat16(b.x); p[2].y = __float2bfloat16(b.y);
    p[3].x = __float2bfloat16(b.z); p[3].y = __float2bfloat16(b.w);
    *(float4*)&outp[(size_t)i * 8] = packed;
}

// ---------------- W (K x Nout fp32) -> transposed split planes Wt[n][k] bf16 ----------------
__global__ __launch_bounds__(256) void wsplit_kernel(
    const float* __restrict__ W, int nout,
    __hip_bfloat16* __restrict__ Whi, __hip_bfloat16* __restrict__ Wlo)
{
    int i = blockIdx.x * 256 + threadIdx.x;   // over 128*nout
    if (i >= 128 * nout) return;
    int k = i / nout, n = i - k * nout;
    float v = W[i];
    __hip_bfloat16 h, l;
    bf_split(v, h, l);
    Whi[n * 128 + k] = h;
    Wlo[n * 128 + k] = l;
}

// ---------------- pull aggregation: 16-lane group per dst row, bf16 features ----
template<int W, bool SCALE_SRC, bool SPLIT_OUT, bool BIAS>
__global__ __launch_bounds__(256) void gather_kernel(
    const __hip_bfloat16* __restrict__ h, const int* __restrict__ csr,
    const int* __restrict__ row_start, const float* __restrict__ norm_out,
    const float* __restrict__ norm_in, const float* __restrict__ bias,
    float* __restrict__ outf, __hip_bfloat16* __restrict__ ohi,
    __hip_bfloat16* __restrict__ olo)
{
    int tid = blockIdx.x * 256 + threadIdx.x;
    int row = tid >> 4;                 // 16 lanes per row
    int l = threadIdx.x & 15;           // lane within group
    int gbase = threadIdx.x & 48;       // group's base lane within the wave
    if (row >= N_NODES) return;
    int beg = row_start[row];
    int end = row_start[row + 1];
    float acc[8] = {};
    for (int j = beg; j < end; j += 16) {
        int cnt = min(16, end - j);
        int sv = 0;
        float nv = 0.f;
        if (j + l < end) {
            sv = csr[j + l];                       // coalesced edge-id load
            if (SCALE_SRC) nv = norm_out[sv];
        }
        for (int i = 0; i < cnt; i++) {
            int s = __shfl(sv, gbase + i);
            if (W == 128) {
                float4 raw = *(const float4*)(h + (size_t)s * 128 + l * 8);
                const __hip_bfloat162* pp = (const __hip_bfloat162*)&raw;
                float2 f0 = __bfloat1622float2(pp[0]);
                float2 f1 = __bfloat1622float2(pp[1]);
                float2 f2 = __bfloat1622float2(pp[2]);
                float2 f3 = __bfloat1622float2(pp[3]);
                if (SCALE_SRC) {
                    float sc = __shfl(nv, gbase + i);
                    acc[0] += f0.x * sc; acc[1] += f0.y * sc;
                    acc[2] += f1.x * sc; acc[3] += f1.y * sc;
                    acc[4] += f2.x * sc; acc[5] += f2.y * sc;
                    acc[6] += f3.x * sc; acc[7] += f3.y * sc;
                } else {
                    acc[0] += f0.x; acc[1] += f0.y;
                    acc[2] += f1.x; acc[3] += f1.y;
                    acc[4] += f2.x; acc[5] += f2.y;
                    acc[6] += f3.x; acc[7] += f3.y;
                }
            } else {
                float2 raw = *(const float2*)(h + (size_t)s * 64 + l * 4);
                const __hip_bfloat162* pp = (const __hip_bfloat162*)&raw;
                float2 f0 = __bfloat1622float2(pp[0]);
                float2 f1 = __bfloat1622float2(pp[1]);
                acc[0] += f0.x; acc[1] += f0.y;
                acc[2] += f1.x; acc[3] += f1.y;
            }
        }
    }
    float ni = norm_in[row];
    if (W == 128 && SPLIT_OUT) {
        float4 ph, pl;
        __hip_bfloat16* hp = (__hip_bfloat16*)&ph;
        __hip_bfloat16* lp = (__hip_bfloat16*)&pl;
        #pragma unroll
        for (int j = 0; j < 8; j++) bf_split(acc[j] * ni, hp[j], lp[j]);
        *(float4*)(ohi + (size_t)row * 128 + l * 8) = ph;
        *(float4*)(olo + (size_t)row * 128 + l * 8) = pl;
    } else if (W == 64) {
        float4 o0 = make_float4(acc[0] * ni, acc[1] * ni, acc[2] * ni, acc[3] * ni);
        if (BIAS) {
            float4 b = *(const float4*)&bias[l * 4];
            o0.x += b.x; o0.y += b.y; o0.z += b.z; o0.w += b.w;
        }
        *(float4*)&outf[(size_t)row * 64 + l * 4] = o0;
    }
}

// ---------------- MFMA GEMM: out = act(A @ W + b) * rowscale ----------------
template<int NT, bool RELU, bool BIAS, bool RS, bool SPLIT_OUT>
__global__ __launch_bounds__(256) void mfma_matmul_kernel(
    const __hip_bfloat16* __restrict__ Ahi, const __hip_bfloat16* __restrict__ Alo,
    const __hip_bfloat16* __restrict__ Wthi, const __hip_bfloat16* __restrict__ Wtlo,
    const float* __restrict__ bias, const float* __restrict__ rowscale,
    __hip_bfloat16* __restrict__ outhi, __hip_bfloat16* __restrict__ outlo,
    int nrows)
{
    const int OUTW = NT * 16;
    const int wave = threadIdx.x >> 6;
    const int lane = threadIdx.x & 63;
    const int n = lane & 15;
    const int q = lane >> 4;
    const int r0 = blockIdx.x * 128 + wave * 32;
    if (r0 >= nrows) return;
    const bool t1 = (r0 + 16) < nrows;
    const size_t a0off = (size_t)(r0 + n) * 128 + q * 8;
    const size_t a1off = (size_t)(t1 ? (r0 + 16 + n) : (r0 + n)) * 128 + q * 8;
    const size_t bbase = (size_t)n * 128 + q * 8;

    f32x4 acc0[NT], acc1[NT];
    const f32x4 zero = {0.f, 0.f, 0.f, 0.f};
    #pragma unroll
    for (int ct = 0; ct < NT; ct++) { acc0[ct] = zero; acc1[ct] = zero; }

    #pragma unroll 1
    for (int kc = 0; kc < 4; kc++) {
        bf16x8 ah0 = *(const bf16x8*)(Ahi + a0off + kc * 32);
        bf16x8 al0 = *(const bf16x8*)(Alo + a0off + kc * 32);
        bf16x8 ah1 = *(const bf16x8*)(Ahi + a1off + kc * 32);
        bf16x8 al1 = *(const bf16x8*)(Alo + a1off + kc * 32);
        #pragma unroll
        for (int ct = 0; ct < NT; ct++) {
            bf16x8 bh = *(const bf16x8*)(Wthi + (size_t)ct * 2048 + bbase + kc * 32);
            bf16x8 bl = *(const bf16x8*)(Wtlo + (size_t)ct * 2048 + bbase + kc * 32);
            acc0[ct] = __builtin_amdgcn_mfma_f32_16x16x32_bf16(ah0, bh, acc0[ct], 0, 0, 0);
            acc0[ct] = __builtin_amdgcn_mfma_f32_16x16x32_bf16(al0, bh, acc0[ct], 0, 0, 0);
            acc0[ct] = __builtin_amdgcn_mfma_f32_16x16x32_bf16(ah0, bl, acc0[ct], 0, 0, 0);
            acc1[ct] = __builtin_amdgcn_mfma_f32_16x16x32_bf16(ah1, bh, acc1[ct], 0, 0, 0);
            acc1[ct] = __builtin_amdgcn_mfma_f32_16x16x32_bf16(al1, bh, acc1[ct], 0, 0, 0);
            acc1[ct] = __builtin_amdgcn_mfma_f32_16x16x32_bf16(ah1, bl, acc1[ct], 0, 0, 0);
        }
    }

    float bcol[NT];
    #pragma unroll
    for (int ct = 0; ct < NT; ct++) bcol[ct] = BIAS ? bias[ct * 16 + n] : 0.f;

    #pragma unroll
    for (int r = 0; r < 4; r++) {
        int grow = r0 + q * 4 + r;
        float rs = RS ? rowscale[grow] : 1.f;
        #pragma unroll
        for (int ct = 0; ct < NT; ct++) {
            float v = acc0[ct][r] + bcol[ct];
            if (RELU) v = fmaxf(v, 0.f);
            v *= rs;
            size_t o = (size_t)grow * OUTW + ct * 16 + n;
            if (SPLIT_OUT) {
                __hip_bfloat16 h, l;
                bf_split(v, h, l);
                outhi[o] = h; outlo[o] = l;
            } else {
                outhi[o] = __float2bfloat16(v);
            }
        }
    }
    if (t1) {
        #pragma unroll
        for (int r = 0; r < 4; r++) {
            int grow = r0 + 16 + q * 4 + r;
            float rs = RS ? rowscale[grow] : 1.f;
            #pragma unroll
            for (int ct = 0; ct < NT; ct++) {
                float v = acc1[ct][r] + bcol[ct];
                if (RELU) v = fmaxf(v, 0.f);
                v *= rs;
                size_t o = (size_t)grow * OUTW + ct * 16 + n;
                if (SPLIT_OUT) {
                    __hip_bfloat16 h, l;
                    bf_split(v, h, l);
                    outhi[o] = h; outlo[o] = l;
                } else {
                    outhi[o] = __float2bfloat16(v);
                }
            }
        }
    }
}

extern "C" void kernel_launch(void* const* d_in, const int* in_sizes, int n_in,
                              void* d_out, int out_size, void* d_ws, size_t ws_size,
                              hipStream_t stream)
{
    const float* feat = (const float*)d_in[0];
    const int* src    = (const int*)d_in[1];
    const int* dst    = (const int*)d_in[2];
    const float* W0   = (const float*)d_in[3];
    const float* b0   = (const float*)d_in[4];
    const float* W1   = (const float*)d_in[5];
    const float* b1   = (const float*)d_in[6];
    const float* W2   = (const float*)d_in[7];
    const float* b2   = (const float*)d_in[8];
    float* out = (float*)d_out;

    const int N = N_NODES;
    const int E = N_EDGES;

    // ---- workspace layout ----
    char* ws = (char*)d_ws;
    float* norm_out = (float*)ws;                    // N
    float* norm_in  = norm_out + N;                  // N
    int* row_start  = (int*)(norm_in + N);           // N+1 (padded to 170004)
    int* csr        = row_start + 170004;            // E
    __hip_bfloat16* Wt0hi = (__hip_bfloat16*)(csr + E);   // 16384 each
    __hip_bfloat16* Wt0lo = Wt0hi + 16384;
    __hip_bfloat16* Wt1hi = Wt0lo + 16384;
    __hip_bfloat16* Wt1lo = Wt1hi + 16384;
    __hip_bfloat16* Wt2hi = Wt1lo + 16384;           // 8192 each
    __hip_bfloat16* Wt2lo = Wt2hi + 8192;
    __hip_bfloat16* bfbuf = Wt2lo + 8192;            // N*128 (featbf -> h1bf -> tbf)
    __hip_bfloat16* Ahi   = bfbuf + (size_t)N * 128; // N*128
    __hip_bfloat16* Alo   = Ahi + (size_t)N * 128;   // N*128
    // CSR-build scratch aliases A planes (dead until gather1, which runs
    // strictly after the build in stream order):
    //   histA (raw) + scanA (scanned) + blockSums + partial -> on Ahi
    //   pairs (int2[E], 9.6MB)                              -> on Alo
    int* histA      = (int*)Ahi;                     // HISTA_PAD
    int* scanA      = histA + HISTA_PAD;             // SCAN_A_PAD + 4
    int* blockSumsA = scanA + SCAN_A_PAD + 4;        // 256
    int* partial    = blockSumsA + 256;              // NSLICE * N
    int2* pairs     = (int2*)Alo;                    // E

    // ---- CSR + norms build (no global atomics) ----
    degout_hist_kernel<<<NCHUNK * NSLICE, 256, 0, stream>>>(src, partial, E);
    degout_combine_kernel<<<(N + 255) / 256, 256, 0, stream>>>(partial, norm_out, N);
    coarse_hist_kernel<<<NB_A, 256, 0, stream>>>(dst, histA, E);
    scan1_kernel<<<SCAN_A_BLOCKS, 256, 0, stream>>>(histA, scanA, blockSumsA, SCAN_A_N);
    scan2_kernel<<<1, 256, 0, stream>>>(blockSumsA, SCAN_A_BLOCKS);
    scan3_kernel<<<SCAN_A_BLOCKS, 256, 0, stream>>>(scanA, blockSumsA);
    coarse_scatter_kernel<<<NB_A, 256, 0, stream>>>(src, dst, scanA, pairs, E);
    bucket_sort_kernel<<<NCB, 256, 0, stream>>>(pairs, scanA, csr, row_start, norm_in, E);
    f2bf_kernel<<<(N * 16 + 255) / 256, 256, 0, stream>>>(feat, bfbuf, N * 16);
    wsplit_kernel<<<64, 256, 0, stream>>>(W0, 128, Wt0hi, Wt0lo);
    wsplit_kernel<<<64, 256, 0, stream>>>(W1, 128, Wt1hi, Wt1lo);
    wsplit_kernel<<<32, 256, 0, stream>>>(W2, 64, Wt2hi, Wt2lo);

    const int gatherBlocks = (N * 16 + 255) / 256;   // 16 lanes/row
    const int mmBlocks = (N + 127) / 128;            // 128 rows/block (2 tiles/wave)

    // ---- Layer 1: agg(featbf*no)*ni -> A split; relu(A@W0+b0)*no -> h1bf
    gather_kernel<128, true, true, false><<<gatherBlocks, 256, 0, stream>>>(
        bfbuf, csr, row_start, norm_out, norm_in, nullptr, nullptr, Ahi, Alo);
    mfma_matmul_kernel<8, true, true, true, false><<<mmBlocks, 256, 0, stream>>>(
        Ahi, Alo, Wt0hi, Wt0lo, b0, norm_out, bfbuf, nullptr, N);

    // ---- Layer 2: agg(h1bf)*ni -> A split; relu(A@W1+b1)*no -> A split (in-place)
    gather_kernel<128, false, true, false><<<gatherBlocks, 256, 0, stream>>>(
        bfbuf, csr, row_start, nullptr, norm_in, nullptr, nullptr, Ahi, Alo);
    mfma_matmul_kernel<8, true, true, true, true><<<mmBlocks, 256, 0, stream>>>(
        Ahi, Alo, Wt1hi, Wt1lo, b1, norm_out, Ahi, Alo, N);

    // ---- Layer 3 (commuted): tbf = bf16(h2@W2); out = agg(tbf)*ni + b2
    mfma_matmul_kernel<4, false, false, false, false><<<mmBlocks, 256, 0, stream>>>(
        Ahi, Alo, Wt2hi, Wt2lo, nullptr, nullptr, bfbuf, nullptr, N);
    gather_kernel<64, false, false, true><<<gatherBlocks, 256, 0, stream>>>(
        bfbuf, csr, row_start, nullptr, norm_in, b2, out, nullptr, nullptr);
}

// Round 5
// 638.121 us; speedup vs baseline: 1.1677x; 1.1677x over previous
//
#include <hip/hip_runtime.h>
#include <hip/hip_bf16.h>

#define N_NODES 170000
#define N_EDGES 1200000

// ---- coarse/fine counting sort geometry ----
#define AITEMS 2048              // edges per coarse block
#define NB_A   586               // ceil(E / AITEMS)
#define NCB    333               // coarse buckets = ceil(N / 512), key = dst>>9
#define SCAN_A_N      (NCB * NB_A)        // 195138 counters
#define SCAN_A_BLOCKS 191                 // ceil(SCAN_A_N / 1024)
#define SCAN_A_PAD    (SCAN_A_BLOCKS * 1024)
#define HISTA_PAD     195140              // SCAN_A_N padded to 16B

// ---- deg_out packed-LDS histogram geometry ----
// Round-4 lesson: 176-block grid = ~1 wave/SIMD -> latency-serialized
// (1100 cyc/iter, occupancy 7.7%). Fix = parallelism: 2 nodes packed per
// LDS word (32KB/chunk -> 4 blocks/CU), 96 slices -> 1056 blocks, int4
// edge loads. Per-slice counts < 65536 so packed halves can't overflow.
#define DOUT_NPC    16384        // nodes per chunk (packed 2/word = 32KB)
#define DOUT_WPC    8192         // words per chunk
#define DOUT_NCHUNK 11           // ceil(N / DOUT_NPC)
#define DOUT_NSLICE 96           // E/96 = 12500 exactly (16B-aligned slices)
#define DOUT_SLICE_E (N_EDGES / DOUT_NSLICE)
#define WORDS_N     85000        // N/2 words over all nodes

typedef short bf16x8 __attribute__((ext_vector_type(8)));
typedef float f32x4 __attribute__((ext_vector_type(4)));

__device__ __forceinline__ void bf_split(float v, __hip_bfloat16& h, __hip_bfloat16& l)
{
    h = __float2bfloat16(v);
    l = __float2bfloat16(v - __bfloat162float(h));
}

// =====================================================================
// CSR build, zero global atomics (round-2 lesson: atomic scope does not
// change memory-side RMW routing on gfx950). Deterministic two-phase
// counting sort with LDS atomics + exclusively-owned global slots.
// =====================================================================

// ---- coarse histogram: per-block 333 counters of dst>>9, digit-major out ----
__global__ __launch_bounds__(256) void coarse_hist_kernel(
    const int* __restrict__ dst, int* __restrict__ histA, int nedges)
{
    __shared__ int h[NCB];
    int t = threadIdx.x;
    for (int j = t; j < NCB; j += 256) h[j] = 0;
    __syncthreads();
    int base = blockIdx.x * AITEMS;
    #pragma unroll
    for (int j = 0; j < AITEMS / 256; j++) {
        int i = base + j * 256 + t;
        if (i < nedges) atomicAdd(&h[dst[i] >> 9], 1);   // LDS atomic
    }
    __syncthreads();
    for (int j = t; j < NCB; j += 256)
        histA[j * NB_A + blockIdx.x] = h[j];
}

// ---- 3-phase exclusive scan (generic, reused for histA) ----
__global__ __launch_bounds__(256) void scan1_kernel(
    const int* __restrict__ in, int* __restrict__ partial,
    int* __restrict__ blockSums, int n)
{
    __shared__ int sdata[256];
    int t = threadIdx.x;
    int base = blockIdx.x * 1024 + t * 4;
    int4 v = make_int4(0, 0, 0, 0);
    if (base + 3 < n) v = *(const int4*)&in[base];
    else {
        if (base + 0 < n) v.x = in[base + 0];
        if (base + 1 < n) v.y = in[base + 1];
        if (base + 2 < n) v.z = in[base + 2];
        if (base + 3 < n) v.w = in[base + 3];
    }
    int tsum = v.x + v.y + v.z + v.w;
    sdata[t] = tsum;
    __syncthreads();
    for (int off = 1; off < 256; off <<= 1) {
        int add = 0;
        if (t >= off) add = sdata[t - off];
        __syncthreads();
        if (t >= off) sdata[t] += add;
        __syncthreads();
    }
    int excl = sdata[t] - tsum;
    int4 o;
    o.x = excl;
    o.y = o.x + v.x;
    o.z = o.y + v.y;
    o.w = o.z + v.z;
    *(int4*)&partial[base] = o;
    if (t == 255) blockSums[blockIdx.x] = sdata[255];
}

__global__ __launch_bounds__(256) void scan2_kernel(int* __restrict__ blockSums, int nb)
{
    __shared__ int sdata[256];
    int t = threadIdx.x;
    int val = (t < nb) ? blockSums[t] : 0;
    sdata[t] = val;
    __syncthreads();
    for (int off = 1; off < 256; off <<= 1) {
        int add = 0;
        if (t >= off) add = sdata[t - off];
        __syncthreads();
        if (t >= off) sdata[t] += add;
        __syncthreads();
    }
    if (t < nb) blockSums[t] = sdata[t] - val;   // exclusive
}

__global__ __launch_bounds__(256) void scan3_kernel(
    int* __restrict__ buf, const int* __restrict__ blockSums)
{
    int off = blockSums[blockIdx.x];
    int base = blockIdx.x * 1024 + threadIdx.x * 4;
    int4 v = *(const int4*)&buf[base];
    v.x += off; v.y += off; v.z += off; v.w += off;
    *(int4*)&buf[base] = v;
}

// ---- coarse scatter: packed (src<<9 | dst&511) into coarse-bucket regions ----
// slot = scanA[digit][block] + LDS-rank; slot sets exclusive per (block,digit).
// Packing halves the scattered write payload vs int2 (src < 2^18 -> 27 bits).
__global__ __launch_bounds__(256) void coarse_scatter_kernel(
    const int* __restrict__ src, const int* __restrict__ dst,
    const int* __restrict__ scanA, int* __restrict__ pairs, int nedges)
{
    __shared__ int base[NCB];
    __shared__ int cur[NCB];
    int t = threadIdx.x;
    for (int j = t; j < NCB; j += 256) {
        base[j] = scanA[j * NB_A + blockIdx.x];
        cur[j] = 0;
    }
    __syncthreads();
    int eb = blockIdx.x * AITEMS;
    #pragma unroll
    for (int j = 0; j < AITEMS / 256; j++) {
        int i = eb + j * 256 + t;
        if (i < nedges) {
            int d = dst[i];
            int cb = d >> 9;
            int r = atomicAdd(&cur[cb], 1);          // LDS atomic-return
            pairs[base[cb] + r] = (src[i] << 9) | (d & 511);
        }
    }
}

// ---- fine phase: one workgroup per coarse bucket ----
// LDS 512-hist of key&511 == deg_in for the bucket's nodes -> norm_in +
// row_start written directly; then re-read bucket, scatter src into csr.
__global__ __launch_bounds__(256) void bucket_sort_kernel(
    const int* __restrict__ pairs, const int* __restrict__ scanA,
    int* __restrict__ csr, int* __restrict__ row_start,
    float* __restrict__ norm_in, int nedges)
{
    __shared__ int hist[512];
    __shared__ int curs[512];
    __shared__ int sdata[256];
    int cb = blockIdx.x;
    int t = threadIdx.x;
    int beg = scanA[cb * NB_A];
    int end = (cb == NCB - 1) ? nedges : scanA[(cb + 1) * NB_A];

    hist[t] = 0; hist[t + 256] = 0;
    __syncthreads();
    for (int j = beg + t; j < end; j += 256)
        atomicAdd(&hist[pairs[j] & 511], 1);
    __syncthreads();

    // exclusive scan of 512 counters (pairwise + Hillis-Steele over 256)
    int a = hist[2 * t], b = hist[2 * t + 1];
    sdata[t] = a + b;
    __syncthreads();
    for (int off = 1; off < 256; off <<= 1) {
        int add = 0;
        if (t >= off) add = sdata[t - off];
        __syncthreads();
        if (t >= off) sdata[t] += add;
        __syncthreads();
    }
    int epair = sdata[t] - (a + b);
    curs[2 * t]     = beg + epair;
    curs[2 * t + 1] = beg + epair + a;
    __syncthreads();

    int nodeBase = cb << 9;
    for (int s = t; s < 512; s += 256) {
        int v = nodeBase + s;
        if (v < N_NODES) {
            row_start[v] = curs[s];
            norm_in[v] = rsqrtf(fmaxf((float)hist[s], 1.0f));
        }
    }
    if (cb == NCB - 1 && t == 0) row_start[N_NODES] = nedges;
    __syncthreads();

    for (int j = beg + t; j < end; j += 256) {
        int p = pairs[j];
        int pos = atomicAdd(&curs[p & 511], 1);      // LDS atomic-return
        csr[pos] = p >> 9;
    }
}

// ---- deg_out: packed-LDS replay histogram, high-parallelism version ----
// Block (chunk,slice): count src in [chunk*16384, ...) over a 12500-edge
// slice; 2 nodes/LDS-word (packed u16 halves, atomicAdd of 1<<((a&1)*16));
// int4 edge loads; write exclusive region of packed partial words.
__global__ __launch_bounds__(256) void degout_hist_kernel(
    const int* __restrict__ src, unsigned* __restrict__ partial)
{
    __shared__ unsigned h[DOUT_WPC];
    int chunk = blockIdx.x / DOUT_NSLICE;
    int slice = blockIdx.x % DOUT_NSLICE;
    int lo = chunk * DOUT_NPC;
    int t = threadIdx.x;
    #pragma unroll
    for (int j = 0; j < DOUT_WPC / 256; j++) h[j * 256 + t] = 0;
    __syncthreads();
    const int4* sp = (const int4*)(src + slice * DOUT_SLICE_E);
    for (int i = t; i < DOUT_SLICE_E / 4; i += 256) {
        int4 v = sp[i];
        unsigned a = (unsigned)(v.x - lo);
        if (a < DOUT_NPC) atomicAdd(&h[a >> 1], 1u << ((a & 1) * 16));
        a = (unsigned)(v.y - lo);
        if (a < DOUT_NPC) atomicAdd(&h[a >> 1], 1u << ((a & 1) * 16));
        a = (unsigned)(v.z - lo);
        if (a < DOUT_NPC) atomicAdd(&h[a >> 1], 1u << ((a & 1) * 16));
        a = (unsigned)(v.w - lo);
        if (a < DOUT_NPC) atomicAdd(&h[a >> 1], 1u << ((a & 1) * 16));
    }
    __syncthreads();
    int wlo = chunk * DOUT_WPC;
    int nw = min(DOUT_WPC, WORDS_N - wlo);
    for (int j = t; j < nw; j += 256)
        partial[(size_t)slice * WORDS_N + wlo + j] = h[j];
}

__global__ __launch_bounds__(256) void degout_combine_kernel(
    const unsigned* __restrict__ partial, float* __restrict__ norm_out)
{
    int w = blockIdx.x * 256 + threadIdx.x;
    if (w >= WORDS_N) return;
    unsigned slo = 0, shi = 0;
    #pragma unroll
    for (int s = 0; s < DOUT_NSLICE; s++) {
        unsigned x = partial[(size_t)s * WORDS_N + w];
        slo += x & 0xFFFFu;
        shi += x >> 16;
    }
    norm_out[2 * w]     = rsqrtf(fmaxf((float)slo, 1.0f));
    norm_out[2 * w + 1] = rsqrtf(fmaxf((float)shi, 1.0f));
}

// ---------------- fp32 -> bf16 row cast (feat) ----------------
__global__ __launch_bounds__(256) void f2bf_kernel(
    const float* __restrict__ in, __hip_bfloat16* __restrict__ outp, int n8)
{
    int i = blockIdx.x * 256 + threadIdx.x;
    if (i >= n8) return;
    float4 a = *(const float4*)&in[(size_t)i * 8];
    float4 b = *(const float4*)&in[(size_t)i * 8 + 4];
    float4 packed;
    __hip_bfloat162* p = (__hip_bfloat162*)&packed;
    p[0].x = __float2bfloat16(a.x); p[0].y = __float2bfloat16(a.y);
    p[1].x = __float2bfloat16(a.z); p[1].y = __float2bfloat16(a.w);
    p[2].x = __float2bfloat16(b.x); p[2].y = __float2bfloat16(b.y);
    p[3].x = __float2bfloat16(b.z); p[3].y = __float2bfloat16(b.w);
    *(float4*)&outp[(size_t)i * 8] = packed;
}

// ---------------- W (K x Nout fp32) -> transposed split planes Wt[n][k] bf16 ----------------
__global__ __launch_bounds__(256) void wsplit_kernel(
    const float* __restrict__ W, int nout,
    __hip_bfloat16* __restrict__ Whi, __hip_bfloat16* __restrict__ Wlo)
{
    int i = blockIdx.x * 256 + threadIdx.x;   // over 128*nout
    if (i >= 128 * nout) return;
    int k = i / nout, n = i - k * nout;
    float v = W[i];
    __hip_bfloat16 h, l;
    bf_split(v, h, l);
    Whi[n * 128 + k] = h;
    Wlo[n * 128 + k] = l;
}

// ---------------- pull aggregation: 16-lane group per dst row, bf16 features ----
template<int W, bool SCALE_SRC, bool SPLIT_OUT, bool BIAS>
__global__ __launch_bounds__(256) void gather_kernel(
    const __hip_bfloat16* __restrict__ h, const int* __restrict__ csr,
    const int* __restrict__ row_start, const float* __restrict__ norm_out,
    const float* __restrict__ norm_in, const float* __restrict__ bias,
    float* __restrict__ outf, __hip_bfloat16* __restrict__ ohi,
    __hip_bfloat16* __restrict__ olo)
{
    int tid = blockIdx.x * 256 + threadIdx.x;
    int row = tid >> 4;                 // 16 lanes per row
    int l = threadIdx.x & 15;           // lane within group
    int gbase = threadIdx.x & 48;       // group's base lane within the wave
    if (row >= N_NODES) return;
    int beg = row_start[row];
    int end = row_start[row + 1];
    float acc[8] = {};
    for (int j = beg; j < end; j += 16) {
        int cnt = min(16, end - j);
        int sv = 0;
        float nv = 0.f;
        if (j + l < end) {
            sv = csr[j + l];                       // coalesced edge-id load
            if (SCALE_SRC) nv = norm_out[sv];
        }
        for (int i = 0; i < cnt; i++) {
            int s = __shfl(sv, gbase + i);
            if (W == 128) {
                float4 raw = *(const float4*)(h + (size_t)s * 128 + l * 8);
                const __hip_bfloat162* pp = (const __hip_bfloat162*)&raw;
                float2 f0 = __bfloat1622float2(pp[0]);
                float2 f1 = __bfloat1622float2(pp[1]);
                float2 f2 = __bfloat1622float2(pp[2]);
                float2 f3 = __bfloat1622float2(pp[3]);
                if (SCALE_SRC) {
                    float sc = __shfl(nv, gbase + i);
                    acc[0] += f0.x * sc; acc[1] += f0.y * sc;
                    acc[2] += f1.x * sc; acc[3] += f1.y * sc;
                    acc[4] += f2.x * sc; acc[5] += f2.y * sc;
                    acc[6] += f3.x * sc; acc[7] += f3.y * sc;
                } else {
                    acc[0] += f0.x; acc[1] += f0.y;
                    acc[2] += f1.x; acc[3] += f1.y;
                    acc[4] += f2.x; acc[5] += f2.y;
                    acc[6] += f3.x; acc[7] += f3.y;
                }
            } else {
                float2 raw = *(const float2*)(h + (size_t)s * 64 + l * 4);
                const __hip_bfloat162* pp = (const __hip_bfloat162*)&raw;
                float2 f0 = __bfloat1622float2(pp[0]);
                float2 f1 = __bfloat1622float2(pp[1]);
                acc[0] += f0.x; acc[1] += f0.y;
                acc[2] += f1.x; acc[3] += f1.y;
            }
        }
    }
    float ni = norm_in[row];
    if (W == 128 && SPLIT_OUT) {
        float4 ph, pl;
        __hip_bfloat16* hp = (__hip_bfloat16*)&ph;
        __hip_bfloat16* lp = (__hip_bfloat16*)&pl;
        #pragma unroll
        for (int j = 0; j < 8; j++) bf_split(acc[j] * ni, hp[j], lp[j]);
        *(float4*)(ohi + (size_t)row * 128 + l * 8) = ph;
        *(float4*)(olo + (size_t)row * 128 + l * 8) = pl;
    } else if (W == 64) {
        float4 o0 = make_float4(acc[0] * ni, acc[1] * ni, acc[2] * ni, acc[3] * ni);
        if (BIAS) {
            float4 b = *(const float4*)&bias[l * 4];
            o0.x += b.x; o0.y += b.y; o0.z += b.z; o0.w += b.w;
        }
        *(float4*)&outf[(size_t)row * 64 + l * 4] = o0;
    }
}

// ---------------- MFMA GEMM: out = act(A @ W + b) * rowscale ----------------
template<int NT, bool RELU, bool BIAS, bool RS, bool SPLIT_OUT>
__global__ __launch_bounds__(256) void mfma_matmul_kernel(
    const __hip_bfloat16* __restrict__ Ahi, const __hip_bfloat16* __restrict__ Alo,
    const __hip_bfloat16* __restrict__ Wthi, const __hip_bfloat16* __restrict__ Wtlo,
    const float* __restrict__ bias, const float* __restrict__ rowscale,
    __hip_bfloat16* __restrict__ outhi, __hip_bfloat16* __restrict__ outlo,
    int nrows)
{
    const int OUTW = NT * 16;
    const int wave = threadIdx.x >> 6;
    const int lane = threadIdx.x & 63;
    const int n = lane & 15;
    const int q = lane >> 4;
    const int r0 = blockIdx.x * 128 + wave * 32;
    if (r0 >= nrows) return;
    const bool t1 = (r0 + 16) < nrows;
    const size_t a0off = (size_t)(r0 + n) * 128 + q * 8;
    const size_t a1off = (size_t)(t1 ? (r0 + 16 + n) : (r0 + n)) * 128 + q * 8;
    const size_t bbase = (size_t)n * 128 + q * 8;

    f32x4 acc0[NT], acc1[NT];
    const f32x4 zero = {0.f, 0.f, 0.f, 0.f};
    #pragma unroll
    for (int ct = 0; ct < NT; ct++) { acc0[ct] = zero; acc1[ct] = zero; }

    #pragma unroll 1
    for (int kc = 0; kc < 4; kc++) {
        bf16x8 ah0 = *(const bf16x8*)(Ahi + a0off + kc * 32);
        bf16x8 al0 = *(const bf16x8*)(Alo + a0off + kc * 32);
        bf16x8 ah1 = *(const bf16x8*)(Ahi + a1off + kc * 32);
        bf16x8 al1 = *(const bf16x8*)(Alo + a1off + kc * 32);
        #pragma unroll
        for (int ct = 0; ct < NT; ct++) {
            bf16x8 bh = *(const bf16x8*)(Wthi + (size_t)ct * 2048 + bbase + kc * 32);
            bf16x8 bl = *(const bf16x8*)(Wtlo + (size_t)ct * 2048 + bbase + kc * 32);
            acc0[ct] = __builtin_amdgcn_mfma_f32_16x16x32_bf16(ah0, bh, acc0[ct], 0, 0, 0);
            acc0[ct] = __builtin_amdgcn_mfma_f32_16x16x32_bf16(al0, bh, acc0[ct], 0, 0, 0);
            acc0[ct] = __builtin_amdgcn_mfma_f32_16x16x32_bf16(ah0, bl, acc0[ct], 0, 0, 0);
            acc1[ct] = __builtin_amdgcn_mfma_f32_16x16x32_bf16(ah1, bh, acc1[ct], 0, 0, 0);
            acc1[ct] = __builtin_amdgcn_mfma_f32_16x16x32_bf16(al1, bh, acc1[ct], 0, 0, 0);
            acc1[ct] = __builtin_amdgcn_mfma_f32_16x16x32_bf16(ah1, bl, acc1[ct], 0, 0, 0);
        }
    }

    float bcol[NT];
    #pragma unroll
    for (int ct = 0; ct < NT; ct++) bcol[ct] = BIAS ? bias[ct * 16 + n] : 0.f;

    #pragma unroll
    for (int r = 0; r < 4; r++) {
        int grow = r0 + q * 4 + r;
        float rs = RS ? rowscale[grow] : 1.f;
        #pragma unroll
        for (int ct = 0; ct < NT; ct++) {
            float v = acc0[ct][r] + bcol[ct];
            if (RELU) v = fmaxf(v, 0.f);
            v *= rs;
            size_t o = (size_t)grow * OUTW + ct * 16 + n;
            if (SPLIT_OUT) {
                __hip_bfloat16 h, l;
                bf_split(v, h, l);
                outhi[o] = h; outlo[o] = l;
            } else {
                outhi[o] = __float2bfloat16(v);
            }
        }
    }
    if (t1) {
        #pragma unroll
        for (int r = 0; r < 4; r++) {
            int grow = r0 + 16 + q * 4 + r;
            float rs = RS ? rowscale[grow] : 1.f;
            #pragma unroll
            for (int ct = 0; ct < NT; ct++) {
                float v = acc1[ct][r] + bcol[ct];
                if (RELU) v = fmaxf(v, 0.f);
                v *= rs;
                size_t o = (size_t)grow * OUTW + ct * 16 + n;
                if (SPLIT_OUT) {
                    __hip_bfloat16 h, l;
                    bf_split(v, h, l);
                    outhi[o] = h; outlo[o] = l;
                } else {
                    outhi[o] = __float2bfloat16(v);
                }
            }
        }
    }
}

extern "C" void kernel_launch(void* const* d_in, const int* in_sizes, int n_in,
                              void* d_out, int out_size, void* d_ws, size_t ws_size,
                              hipStream_t stream)
{
    const float* feat = (const float*)d_in[0];
    const int* src    = (const int*)d_in[1];
    const int* dst    = (const int*)d_in[2];
    const float* W0   = (const float*)d_in[3];
    const float* b0   = (const float*)d_in[4];
    const float* W1   = (const float*)d_in[5];
    const float* b1   = (const float*)d_in[6];
    const float* W2   = (const float*)d_in[7];
    const float* b2   = (const float*)d_in[8];
    float* out = (float*)d_out;

    const int N = N_NODES;
    const int E = N_EDGES;

    // ---- workspace layout ----
    char* ws = (char*)d_ws;
    float* norm_out = (float*)ws;                    // N
    float* norm_in  = norm_out + N;                  // N
    int* row_start  = (int*)(norm_in + N);           // N+1 (padded to 170004)
    int* csr        = row_start + 170004;            // E
    __hip_bfloat16* Wt0hi = (__hip_bfloat16*)(csr + E);   // 16384 each
    __hip_bfloat16* Wt0lo = Wt0hi + 16384;
    __hip_bfloat16* Wt1hi = Wt0lo + 16384;
    __hip_bfloat16* Wt1lo = Wt1hi + 16384;
    __hip_bfloat16* Wt2hi = Wt1lo + 16384;           // 8192 each
    __hip_bfloat16* Wt2lo = Wt2hi + 8192;
    __hip_bfloat16* bfbuf = Wt2lo + 8192;            // N*128 (featbf -> h1bf -> tbf)
    __hip_bfloat16* Ahi   = bfbuf + (size_t)N * 128; // N*128
    __hip_bfloat16* Alo   = Ahi + (size_t)N * 128;   // N*128
    // CSR-build scratch aliases A planes (dead until gather1, which runs
    // strictly after the build in stream order):
    //   histA + scanA + blockSums + partial(32.6MB) -> on Ahi (43.5MB)
    //   pairs (int[E], 4.8MB)                       -> on Alo
    int* histA          = (int*)Ahi;                 // HISTA_PAD
    int* scanA          = histA + HISTA_PAD;         // SCAN_A_PAD + 4
    int* blockSumsA     = scanA + SCAN_A_PAD + 4;    // 256
    unsigned* partial   = (unsigned*)(blockSumsA + 256);  // DOUT_NSLICE * WORDS_N
    int* pairs          = (int*)Alo;                 // E

    // ---- CSR + norms build (no global atomics) ----
    degout_hist_kernel<<<DOUT_NCHUNK * DOUT_NSLICE, 256, 0, stream>>>(src, partial);
    degout_combine_kernel<<<(WORDS_N + 255) / 256, 256, 0, stream>>>(partial, norm_out);
    coarse_hist_kernel<<<NB_A, 256, 0, stream>>>(dst, histA, E);
    scan1_kernel<<<SCAN_A_BLOCKS, 256, 0, stream>>>(histA, scanA, blockSumsA, SCAN_A_N);
    scan2_kernel<<<1, 256, 0, stream>>>(blockSumsA, SCAN_A_BLOCKS);
    scan3_kernel<<<SCAN_A_BLOCKS, 256, 0, stream>>>(scanA, blockSumsA);
    coarse_scatter_kernel<<<NB_A, 256, 0, stream>>>(src, dst, scanA, pairs, E);
    bucket_sort_kernel<<<NCB, 256, 0, stream>>>(pairs, scanA, csr, row_start, norm_in, E);
    f2bf_kernel<<<(N * 16 + 255) / 256, 256, 0, stream>>>(feat, bfbuf, N * 16);
    wsplit_kernel<<<64, 256, 0, stream>>>(W0, 128, Wt0hi, Wt0lo);
    wsplit_kernel<<<64, 256, 0, stream>>>(W1, 128, Wt1hi, Wt1lo);
    wsplit_kernel<<<32, 256, 0, stream>>>(W2, 64, Wt2hi, Wt2lo);

    const int gatherBlocks = (N * 16 + 255) / 256;   // 16 lanes/row
    const int mmBlocks = (N + 127) / 128;            // 128 rows/block (2 tiles/wave)

    // ---- Layer 1: agg(featbf*no)*ni -> A split; relu(A@W0+b0)*no -> h1bf
    gather_kernel<128, true, true, false><<<gatherBlocks, 256, 0, stream>>>(
        bfbuf, csr, row_start, norm_out, norm_in, nullptr, nullptr, Ahi, Alo);
    mfma_matmul_kernel<8, true, true, true, false><<<mmBlocks, 256, 0, stream>>>(
        Ahi, Alo, Wt0hi, Wt0lo, b0, norm_out, bfbuf, nullptr, N);

    // ---- Layer 2: agg(h1bf)*ni -> A split; relu(A@W1+b1)*no -> A split (in-place)
    gather_kernel<128, false, true, false><<<gatherBlocks, 256, 0, stream>>>(
        bfbuf, csr, row_start, nullptr, norm_in, nullptr, nullptr, Ahi, Alo);
    mfma_matmul_kernel<8, true, true, true, true><<<mmBlocks, 256, 0, stream>>>(
        Ahi, Alo, Wt1hi, Wt1lo, b1, norm_out, Ahi, Alo, N);

    // ---- Layer 3 (commuted): tbf = bf16(h2@W2); out = agg(tbf)*ni + b2
    mfma_matmul_kernel<4, false, false, false, false><<<mmBlocks, 256, 0, stream>>>(
        Ahi, Alo, Wt2hi, Wt2lo, nullptr, nullptr, bfbuf, nullptr, N);
    gather_kernel<64, false, false, true><<<gatherBlocks, 256, 0, stream>>>(
        bfbuf, csr, row_start, nullptr, norm_in, b2, out, nullptr, nullptr);
}

// Round 6
// 518.703 us; speedup vs baseline: 1.4365x; 1.2302x over previous
//
#include <hip/hip_runtime.h>
#include <hip/hip_bf16.h>

#define N_NODES 170000
#define N_EDGES 1200000

// ---- coarse/fine counting sort geometry ----
#define AITEMS 2048              // edges per coarse block
#define NB_A   586               // ceil(E / AITEMS)
#define NCB    333               // coarse buckets = ceil(N / 512), key = dst>>9
#define SCAN_A_N      (NCB * NB_A)        // 195138 counters
#define SCAN_A_BLOCKS 191                 // ceil(SCAN_A_N / 1024)
#define SCAN_A_PAD    (SCAN_A_BLOCKS * 1024)
#define HISTA_PAD     195140              // SCAN_A_N padded to 16B

// ---- deg_out packed-LDS histogram geometry (round-4 occupancy lesson) ----
#define DOUT_NPC    16384        // nodes per chunk (packed 2/word = 32KB)
#define DOUT_WPC    8192         // words per chunk
#define DOUT_NCHUNK 11           // ceil(N / DOUT_NPC)
#define DOUT_NSLICE 96           // E/96 = 12500 exactly
#define DOUT_SLICE_E (N_EDGES / DOUT_NSLICE)
#define WORDS_N     85000        // N/2 words over all nodes

typedef short bf16x8 __attribute__((ext_vector_type(8)));
typedef float f32x4 __attribute__((ext_vector_type(4)));

__device__ __forceinline__ void bf_split(float v, __hip_bfloat16& h, __hip_bfloat16& l)
{
    h = __float2bfloat16(v);
    l = __float2bfloat16(v - __bfloat162float(h));
}

// Swizzled LDS byte address for a [32][128] bf16 plane (256B row stride).
// XOR of (row&7)<<4 spreads the 16-lane column-slice reads across 8 distinct
// 16B slots -> 2-way residual conflict (free). Same mapping on write & read.
__device__ __forceinline__ int lds_addr(int row, int col)
{
    return (row * 256 + col * 2) ^ ((row & 7) << 4);
}

// =====================================================================
// CSR build, zero global atomics (round-2 lesson: atomic scope does not
// change memory-side RMW routing on gfx950). Deterministic two-phase
// counting sort with LDS atomics + exclusively-owned global slots.
// =====================================================================

__global__ __launch_bounds__(256) void coarse_hist_kernel(
    const int* __restrict__ dst, int* __restrict__ histA, int nedges)
{
    __shared__ int h[NCB];
    int t = threadIdx.x;
    for (int j = t; j < NCB; j += 256) h[j] = 0;
    __syncthreads();
    int base = blockIdx.x * AITEMS;
    #pragma unroll
    for (int j = 0; j < AITEMS / 256; j++) {
        int i = base + j * 256 + t;
        if (i < nedges) atomicAdd(&h[dst[i] >> 9], 1);   // LDS atomic
    }
    __syncthreads();
    for (int j = t; j < NCB; j += 256)
        histA[j * NB_A + blockIdx.x] = h[j];
}

__global__ __launch_bounds__(256) void scan1_kernel(
    const int* __restrict__ in, int* __restrict__ partial,
    int* __restrict__ blockSums, int n)
{
    __shared__ int sdata[256];
    int t = threadIdx.x;
    int base = blockIdx.x * 1024 + t * 4;
    int4 v = make_int4(0, 0, 0, 0);
    if (base + 3 < n) v = *(const int4*)&in[base];
    else {
        if (base + 0 < n) v.x = in[base + 0];
        if (base + 1 < n) v.y = in[base + 1];
        if (base + 2 < n) v.z = in[base + 2];
        if (base + 3 < n) v.w = in[base + 3];
    }
    int tsum = v.x + v.y + v.z + v.w;
    sdata[t] = tsum;
    __syncthreads();
    for (int off = 1; off < 256; off <<= 1) {
        int add = 0;
        if (t >= off) add = sdata[t - off];
        __syncthreads();
        if (t >= off) sdata[t] += add;
        __syncthreads();
    }
    int excl = sdata[t] - tsum;
    int4 o;
    o.x = excl;
    o.y = o.x + v.x;
    o.z = o.y + v.y;
    o.w = o.z + v.z;
    *(int4*)&partial[base] = o;
    if (t == 255) blockSums[blockIdx.x] = sdata[255];
}

__global__ __launch_bounds__(256) void scan2_kernel(int* __restrict__ blockSums, int nb)
{
    __shared__ int sdata[256];
    int t = threadIdx.x;
    int val = (t < nb) ? blockSums[t] : 0;
    sdata[t] = val;
    __syncthreads();
    for (int off = 1; off < 256; off <<= 1) {
        int add = 0;
        if (t >= off) add = sdata[t - off];
        __syncthreads();
        if (t >= off) sdata[t] += add;
        __syncthreads();
    }
    if (t < nb) blockSums[t] = sdata[t] - val;   // exclusive
}

__global__ __launch_bounds__(256) void scan3_kernel(
    int* __restrict__ buf, const int* __restrict__ blockSums)
{
    int off = blockSums[blockIdx.x];
    int base = blockIdx.x * 1024 + threadIdx.x * 4;
    int4 v = *(const int4*)&buf[base];
    v.x += off; v.y += off; v.z += off; v.w += off;
    *(int4*)&buf[base] = v;
}

__global__ __launch_bounds__(256) void coarse_scatter_kernel(
    const int* __restrict__ src, const int* __restrict__ dst,
    const int* __restrict__ scanA, int* __restrict__ pairs, int nedges)
{
    __shared__ int base[NCB];
    __shared__ int cur[NCB];
    int t = threadIdx.x;
    for (int j = t; j < NCB; j += 256) {
        base[j] = scanA[j * NB_A + blockIdx.x];
        cur[j] = 0;
    }
    __syncthreads();
    int eb = blockIdx.x * AITEMS;
    #pragma unroll
    for (int j = 0; j < AITEMS / 256; j++) {
        int i = eb + j * 256 + t;
        if (i < nedges) {
            int d = dst[i];
            int cb = d >> 9;
            int r = atomicAdd(&cur[cb], 1);          // LDS atomic-return
            pairs[base[cb] + r] = (src[i] << 9) | (d & 511);
        }
    }
}

__global__ __launch_bounds__(256) void bucket_sort_kernel(
    const int* __restrict__ pairs, const int* __restrict__ scanA,
    int* __restrict__ csr, int* __restrict__ row_start,
    float* __restrict__ norm_in, int nedges)
{
    __shared__ int hist[512];
    __shared__ int curs[512];
    __shared__ int sdata[256];
    int cb = blockIdx.x;
    int t = threadIdx.x;
    int beg = scanA[cb * NB_A];
    int end = (cb == NCB - 1) ? nedges : scanA[(cb + 1) * NB_A];

    hist[t] = 0; hist[t + 256] = 0;
    __syncthreads();
    for (int j = beg + t; j < end; j += 256)
        atomicAdd(&hist[pairs[j] & 511], 1);
    __syncthreads();

    int a = hist[2 * t], b = hist[2 * t + 1];
    sdata[t] = a + b;
    __syncthreads();
    for (int off = 1; off < 256; off <<= 1) {
        int add = 0;
        if (t >= off) add = sdata[t - off];
        __syncthreads();
        if (t >= off) sdata[t] += add;
        __syncthreads();
    }
    int epair = sdata[t] - (a + b);
    curs[2 * t]     = beg + epair;
    curs[2 * t + 1] = beg + epair + a;
    __syncthreads();

    int nodeBase = cb << 9;
    for (int s = t; s < 512; s += 256) {
        int v = nodeBase + s;
        if (v < N_NODES) {
            row_start[v] = curs[s];
            norm_in[v] = rsqrtf(fmaxf((float)hist[s], 1.0f));
        }
    }
    if (cb == NCB - 1 && t == 0) row_start[N_NODES] = nedges;
    __syncthreads();

    for (int j = beg + t; j < end; j += 256) {
        int p = pairs[j];
        int pos = atomicAdd(&curs[p & 511], 1);      // LDS atomic-return
        csr[pos] = p >> 9;
    }
}

__global__ __launch_bounds__(256) void degout_hist_kernel(
    const int* __restrict__ src, unsigned* __restrict__ partial)
{
    __shared__ unsigned h[DOUT_WPC];
    int chunk = blockIdx.x / DOUT_NSLICE;
    int slice = blockIdx.x % DOUT_NSLICE;
    int lo = chunk * DOUT_NPC;
    int t = threadIdx.x;
    #pragma unroll
    for (int j = 0; j < DOUT_WPC / 256; j++) h[j * 256 + t] = 0;
    __syncthreads();
    const int4* sp = (const int4*)(src + slice * DOUT_SLICE_E);
    for (int i = t; i < DOUT_SLICE_E / 4; i += 256) {
        int4 v = sp[i];
        unsigned a = (unsigned)(v.x - lo);
        if (a < DOUT_NPC) atomicAdd(&h[a >> 1], 1u << ((a & 1) * 16));
        a = (unsigned)(v.y - lo);
        if (a < DOUT_NPC) atomicAdd(&h[a >> 1], 1u << ((a & 1) * 16));
        a = (unsigned)(v.z - lo);
        if (a < DOUT_NPC) atomicAdd(&h[a >> 1], 1u << ((a & 1) * 16));
        a = (unsigned)(v.w - lo);
        if (a < DOUT_NPC) atomicAdd(&h[a >> 1], 1u << ((a & 1) * 16));
    }
    __syncthreads();
    int wlo = chunk * DOUT_WPC;
    int nw = min(DOUT_WPC, WORDS_N - wlo);
    for (int j = t; j < nw; j += 256)
        partial[(size_t)slice * WORDS_N + wlo + j] = h[j];
}

__global__ __launch_bounds__(256) void degout_combine_kernel(
    const unsigned* __restrict__ partial, float* __restrict__ norm_out)
{
    int w = blockIdx.x * 256 + threadIdx.x;
    if (w >= WORDS_N) return;
    unsigned slo = 0, shi = 0;
    #pragma unroll
    for (int s = 0; s < DOUT_NSLICE; s++) {
        unsigned x = partial[(size_t)s * WORDS_N + w];
        slo += x & 0xFFFFu;
        shi += x >> 16;
    }
    norm_out[2 * w]     = rsqrtf(fmaxf((float)slo, 1.0f));
    norm_out[2 * w + 1] = rsqrtf(fmaxf((float)shi, 1.0f));
}

// ---------------- fp32 -> bf16 row cast (feat) ----------------
__global__ __launch_bounds__(256) void f2bf_kernel(
    const float* __restrict__ in, __hip_bfloat16* __restrict__ outp, int n8)
{
    int i = blockIdx.x * 256 + threadIdx.x;
    if (i >= n8) return;
    float4 a = *(const float4*)&in[(size_t)i * 8];
    float4 b = *(const float4*)&in[(size_t)i * 8 + 4];
    float4 packed;
    __hip_bfloat162* p = (__hip_bfloat162*)&packed;
    p[0].x = __float2bfloat16(a.x); p[0].y = __float2bfloat16(a.y);
    p[1].x = __float2bfloat16(a.z); p[1].y = __float2bfloat16(a.w);
    p[2].x = __float2bfloat16(b.x); p[2].y = __float2bfloat16(b.y);
    p[3].x = __float2bfloat16(b.z); p[3].y = __float2bfloat16(b.w);
    *(float4*)&outp[(size_t)i * 8] = packed;
}

// ---------------- W (K x Nout fp32) -> transposed split planes Wt[n][k] bf16 ----
__global__ __launch_bounds__(256) void wsplit_kernel(
    const float* __restrict__ W, int nout,
    __hip_bfloat16* __restrict__ Whi, __hip_bfloat16* __restrict__ Wlo)
{
    int i = blockIdx.x * 256 + threadIdx.x;   // over 128*nout
    if (i >= 128 * nout) return;
    int k = i / nout, n = i - k * nout;
    float v = W[i];
    __hip_bfloat16 h, l;
    bf_split(v, h, l);
    Whi[n * 128 + k] = h;
    Wlo[n * 128 + k] = l;
}

// =====================================================================
// Fused GCN layer: gather 32 dst rows -> swizzled LDS split planes ->
// MFMA GEMM (W, 128 cols) -> epilogue.
// Round-5 lesson: the A-split (gather->matmul) and h2-split (mm2->mm3)
// intermediates each cost a full 87MB HBM write + ~93MB re-read (FETCH
// showed no cache-side service). Fusing keeps them in 16KB of LDS.
// FUSE2: second GEMM (W2, 64 cols) runs on the h2 tile staged back into
// the same LDS planes -> h2 never touches memory either.
// Numerics identical to the unfused path (same bf_split / 3-MFMA split).
// =====================================================================
template<bool SCALE_SRC, bool FUSE2>
__global__ __launch_bounds__(256) void fused_layer_kernel(
    const __hip_bfloat16* __restrict__ hin, const int* __restrict__ csr,
    const int* __restrict__ row_start, const float* __restrict__ norm_out,
    const float* __restrict__ norm_in, const __hip_bfloat16* __restrict__ Wthi,
    const __hip_bfloat16* __restrict__ Wtlo, const float* __restrict__ bias,
    const float* __restrict__ rowscale, const __hip_bfloat16* __restrict__ W2thi,
    const __hip_bfloat16* __restrict__ W2tlo, __hip_bfloat16* __restrict__ outp)
{
    __shared__ __align__(16) unsigned char smem[16384];   // hi @0, lo @8192
    const int r0 = blockIdx.x * 32;

    // ---- phase 1: gather 32 rows (16 groups x 2 rows, 16 lanes/row) ----
    {
        const int g = threadIdx.x >> 4;
        const int l = threadIdx.x & 15;
        const int gbase = threadIdx.x & 48;
        for (int rr = 0; rr < 2; rr++) {
            const int lrow = g + rr * 16;
            const int row = r0 + lrow;
            float acc[8] = {};
            if (row < N_NODES) {
                int beg = row_start[row];
                int end = row_start[row + 1];
                for (int j = beg; j < end; j += 16) {
                    int cnt = min(16, end - j);
                    int sv = 0;
                    float nv = 0.f;
                    if (j + l < end) {
                        sv = csr[j + l];
                        if (SCALE_SRC) nv = norm_out[sv];
                    }
                    for (int i = 0; i < cnt; i++) {
                        int s = __shfl(sv, gbase + i);
                        float4 raw = *(const float4*)(hin + (size_t)s * 128 + l * 8);
                        const __hip_bfloat162* pp = (const __hip_bfloat162*)&raw;
                        float2 f0 = __bfloat1622float2(pp[0]);
                        float2 f1 = __bfloat1622float2(pp[1]);
                        float2 f2 = __bfloat1622float2(pp[2]);
                        float2 f3 = __bfloat1622float2(pp[3]);
                        if (SCALE_SRC) {
                            float sc = __shfl(nv, gbase + i);
                            acc[0] += f0.x * sc; acc[1] += f0.y * sc;
                            acc[2] += f1.x * sc; acc[3] += f1.y * sc;
                            acc[4] += f2.x * sc; acc[5] += f2.y * sc;
                            acc[6] += f3.x * sc; acc[7] += f3.y * sc;
                        } else {
                            acc[0] += f0.x; acc[1] += f0.y;
                            acc[2] += f1.x; acc[3] += f1.y;
                            acc[4] += f2.x; acc[5] += f2.y;
                            acc[6] += f3.x; acc[7] += f3.y;
                        }
                    }
                }
            }
            float ni = (row < N_NODES) ? norm_in[row] : 0.f;  // invalid rows -> zeros
            float4 ph, pl;
            __hip_bfloat16* hp = (__hip_bfloat16*)&ph;
            __hip_bfloat16* lp = (__hip_bfloat16*)&pl;
            #pragma unroll
            for (int jj = 0; jj < 8; jj++) bf_split(acc[jj] * ni, hp[jj], lp[jj]);
            int off = lds_addr(lrow, l * 8);
            *(float4*)(smem + off) = ph;
            *(float4*)(smem + 8192 + off) = pl;
        }
    }
    __syncthreads();

    // ---- phase 2: GEMM1 (128 cols; wave w owns col-tiles 2w, 2w+1) ----
    const int wave = threadIdx.x >> 6;
    const int lane = threadIdx.x & 63;
    const int n = lane & 15;
    const int q = lane >> 4;
    const size_t bbase = (size_t)n * 128 + q * 8;
    const f32x4 zero = {0.f, 0.f, 0.f, 0.f};
    f32x4 acc0[2], acc1[2];
    acc0[0] = zero; acc0[1] = zero; acc1[0] = zero; acc1[1] = zero;

    #pragma unroll 1
    for (int kc = 0; kc < 4; kc++) {
        const int a0 = lds_addr(n, q * 8 + kc * 32);
        const int a1 = lds_addr(n + 16, q * 8 + kc * 32);
        bf16x8 ah0 = *(const bf16x8*)(smem + a0);
        bf16x8 al0 = *(const bf16x8*)(smem + 8192 + a0);
        bf16x8 ah1 = *(const bf16x8*)(smem + a1);
        bf16x8 al1 = *(const bf16x8*)(smem + 8192 + a1);
        #pragma unroll
        for (int c = 0; c < 2; c++) {
            const int ct = wave * 2 + c;
            bf16x8 bh = *(const bf16x8*)(Wthi + (size_t)ct * 2048 + bbase + kc * 32);
            bf16x8 bl = *(const bf16x8*)(Wtlo + (size_t)ct * 2048 + bbase + kc * 32);
            acc0[c] = __builtin_amdgcn_mfma_f32_16x16x32_bf16(ah0, bh, acc0[c], 0, 0, 0);
            acc0[c] = __builtin_amdgcn_mfma_f32_16x16x32_bf16(al0, bh, acc0[c], 0, 0, 0);
            acc0[c] = __builtin_amdgcn_mfma_f32_16x16x32_bf16(ah0, bl, acc0[c], 0, 0, 0);
            acc1[c] = __builtin_amdgcn_mfma_f32_16x16x32_bf16(ah1, bh, acc1[c], 0, 0, 0);
            acc1[c] = __builtin_amdgcn_mfma_f32_16x16x32_bf16(al1, bh, acc1[c], 0, 0, 0);
            acc1[c] = __builtin_amdgcn_mfma_f32_16x16x32_bf16(ah1, bl, acc1[c], 0, 0, 0);
        }
    }

    float bcol[2];
    bcol[0] = bias[(wave * 2 + 0) * 16 + n];
    bcol[1] = bias[(wave * 2 + 1) * 16 + n];

    if (!FUSE2) {
        // epilogue: out = relu(acc + b) * rowscale, [N][128] single bf16
        #pragma unroll
        for (int r = 0; r < 4; r++) {
            int g0 = r0 + q * 4 + r;
            int g1 = g0 + 16;
            float rs0 = rowscale[min(g0, N_NODES - 1)];
            float rs1 = rowscale[min(g1, N_NODES - 1)];
            #pragma unroll
            for (int c = 0; c < 2; c++) {
                int col = (wave * 2 + c) * 16 + n;
                float v0 = fmaxf(acc0[c][r] + bcol[c], 0.f) * rs0;
                float v1 = fmaxf(acc1[c][r] + bcol[c], 0.f) * rs1;
                if (g0 < N_NODES) outp[(size_t)g0 * 128 + col] = __float2bfloat16(v0);
                if (g1 < N_NODES) outp[(size_t)g1 * 128 + col] = __float2bfloat16(v1);
            }
        }
    } else {
        // stage h2' = relu(acc+b)*rowscale back into LDS (split), then GEMM2.
        __syncthreads();   // all waves done reading A planes
        #pragma unroll
        for (int r = 0; r < 4; r++) {
            int lr0 = q * 4 + r;
            int lr1 = lr0 + 16;
            float rs0 = rowscale[min(r0 + lr0, N_NODES - 1)];
            float rs1 = rowscale[min(r0 + lr1, N_NODES - 1)];
            #pragma unroll
            for (int c = 0; c < 2; c++) {
                int col = (wave * 2 + c) * 16 + n;
                float v0 = fmaxf(acc0[c][r] + bcol[c], 0.f) * rs0;
                float v1 = fmaxf(acc1[c][r] + bcol[c], 0.f) * rs1;
                __hip_bfloat16 hh, ll;
                bf_split(v0, hh, ll);
                *(__hip_bfloat16*)(smem + lds_addr(lr0, col)) = hh;
                *(__hip_bfloat16*)(smem + 8192 + lds_addr(lr0, col)) = ll;
                bf_split(v1, hh, ll);
                *(__hip_bfloat16*)(smem + lds_addr(lr1, col)) = hh;
                *(__hip_bfloat16*)(smem + 8192 + lds_addr(lr1, col)) = ll;
            }
        }
        __syncthreads();

        // GEMM2: 64 output cols; wave w owns col-tile w.
        f32x4 c0 = zero, c1 = zero;
        #pragma unroll 1
        for (int kc = 0; kc < 4; kc++) {
            const int a0 = lds_addr(n, q * 8 + kc * 32);
            const int a1 = lds_addr(n + 16, q * 8 + kc * 32);
            bf16x8 ah0 = *(const bf16x8*)(smem + a0);
            bf16x8 al0 = *(const bf16x8*)(smem + 8192 + a0);
            bf16x8 ah1 = *(const bf16x8*)(smem + a1);
            bf16x8 al1 = *(const bf16x8*)(smem + 8192 + a1);
            bf16x8 bh = *(const bf16x8*)(W2thi + (size_t)wave * 2048 + bbase + kc * 32);
            bf16x8 bl = *(const bf16x8*)(W2tlo + (size_t)wave * 2048 + bbase + kc * 32);
            c0 = __builtin_amdgcn_mfma_f32_16x16x32_bf16(ah0, bh, c0, 0, 0, 0);
            c0 = __builtin_amdgcn_mfma_f32_16x16x32_bf16(al0, bh, c0, 0, 0, 0);
            c0 = __builtin_amdgcn_mfma_f32_16x16x32_bf16(ah0, bl, c0, 0, 0, 0);
            c1 = __builtin_amdgcn_mfma_f32_16x16x32_bf16(ah1, bh, c1, 0, 0, 0);
            c1 = __builtin_amdgcn_mfma_f32_16x16x32_bf16(al1, bh, c1, 0, 0, 0);
            c1 = __builtin_amdgcn_mfma_f32_16x16x32_bf16(ah1, bl, c1, 0, 0, 0);
        }
        #pragma unroll
        for (int r = 0; r < 4; r++) {
            int g0 = r0 + q * 4 + r;
            int g1 = g0 + 16;
            int col = wave * 16 + n;
            if (g0 < N_NODES) outp[(size_t)g0 * 64 + col] = __float2bfloat16(c0[r]);
            if (g1 < N_NODES) outp[(size_t)g1 * 64 + col] = __float2bfloat16(c1[r]);
        }
    }
}

// ---------------- final pull aggregation (W=64): out = agg(tbf)*ni + b2 ----
template<int W, bool SCALE_SRC, bool SPLIT_OUT, bool BIAS>
__global__ __launch_bounds__(256) void gather_kernel(
    const __hip_bfloat16* __restrict__ h, const int* __restrict__ csr,
    const int* __restrict__ row_start, const float* __restrict__ norm_out,
    const float* __restrict__ norm_in, const float* __restrict__ bias,
    float* __restrict__ outf, __hip_bfloat16* __restrict__ ohi,
    __hip_bfloat16* __restrict__ olo)
{
    int tid = blockIdx.x * 256 + threadIdx.x;
    int row = tid >> 4;                 // 16 lanes per row
    int l = threadIdx.x & 15;
    int gbase = threadIdx.x & 48;
    if (row >= N_NODES) return;
    int beg = row_start[row];
    int end = row_start[row + 1];
    float acc[8] = {};
    for (int j = beg; j < end; j += 16) {
        int cnt = min(16, end - j);
        int sv = 0;
        float nv = 0.f;
        if (j + l < end) {
            sv = csr[j + l];
            if (SCALE_SRC) nv = norm_out[sv];
        }
        for (int i = 0; i < cnt; i++) {
            int s = __shfl(sv, gbase + i);
            if (W == 128) {
                float4 raw = *(const float4*)(h + (size_t)s * 128 + l * 8);
                const __hip_bfloat162* pp = (const __hip_bfloat162*)&raw;
                float2 f0 = __bfloat1622float2(pp[0]);
                float2 f1 = __bfloat1622float2(pp[1]);
                float2 f2 = __bfloat1622float2(pp[2]);
                float2 f3 = __bfloat1622float2(pp[3]);
                if (SCALE_SRC) {
                    float sc = __shfl(nv, gbase + i);
                    acc[0] += f0.x * sc; acc[1] += f0.y * sc;
                    acc[2] += f1.x * sc; acc[3] += f1.y * sc;
                    acc[4] += f2.x * sc; acc[5] += f2.y * sc;
                    acc[6] += f3.x * sc; acc[7] += f3.y * sc;
                } else {
                    acc[0] += f0.x; acc[1] += f0.y;
                    acc[2] += f1.x; acc[3] += f1.y;
                    acc[4] += f2.x; acc[5] += f2.y;
                    acc[6] += f3.x; acc[7] += f3.y;
                }
            } else {
                float2 raw = *(const float2*)(h + (size_t)s * 64 + l * 4);
                const __hip_bfloat162* pp = (const __hip_bfloat162*)&raw;
                float2 f0 = __bfloat1622float2(pp[0]);
                float2 f1 = __bfloat1622float2(pp[1]);
                acc[0] += f0.x; acc[1] += f0.y;
                acc[2] += f1.x; acc[3] += f1.y;
            }
        }
    }
    float ni = norm_in[row];
    if (W == 128 && SPLIT_OUT) {
        float4 ph, pl;
        __hip_bfloat16* hp = (__hip_bfloat16*)&ph;
        __hip_bfloat16* lp = (__hip_bfloat16*)&pl;
        #pragma unroll
        for (int j = 0; j < 8; j++) bf_split(acc[j] * ni, hp[j], lp[j]);
        *(float4*)(ohi + (size_t)row * 128 + l * 8) = ph;
        *(float4*)(olo + (size_t)row * 128 + l * 8) = pl;
    } else if (W == 64) {
        float4 o0 = make_float4(acc[0] * ni, acc[1] * ni, acc[2] * ni, acc[3] * ni);
        if (BIAS) {
            float4 b = *(const float4*)&bias[l * 4];
            o0.x += b.x; o0.y += b.y; o0.z += b.z; o0.w += b.w;
        }
        *(float4*)&outf[(size_t)row * 64 + l * 4] = o0;
    }
}

extern "C" void kernel_launch(void* const* d_in, const int* in_sizes, int n_in,
                              void* d_out, int out_size, void* d_ws, size_t ws_size,
                              hipStream_t stream)
{
    const float* feat = (const float*)d_in[0];
    const int* src    = (const int*)d_in[1];
    const int* dst    = (const int*)d_in[2];
    const float* W0   = (const float*)d_in[3];
    const float* b0   = (const float*)d_in[4];
    const float* W1   = (const float*)d_in[5];
    const float* b1   = (const float*)d_in[6];
    const float* W2   = (const float*)d_in[7];
    const float* b2   = (const float*)d_in[8];
    float* out = (float*)d_out;

    const int N = N_NODES;
    const int E = N_EDGES;

    // ---- workspace layout ----
    char* ws = (char*)d_ws;
    float* norm_out = (float*)ws;                    // N
    float* norm_in  = norm_out + N;                  // N
    int* row_start  = (int*)(norm_in + N);           // N+1 (padded to 170004)
    int* csr        = row_start + 170004;            // E
    __hip_bfloat16* Wt0hi = (__hip_bfloat16*)(csr + E);   // 16384 each
    __hip_bfloat16* Wt0lo = Wt0hi + 16384;
    __hip_bfloat16* Wt1hi = Wt0lo + 16384;
    __hip_bfloat16* Wt1lo = Wt1hi + 16384;
    __hip_bfloat16* Wt2hi = Wt1lo + 16384;           // 8192 each
    __hip_bfloat16* Wt2lo = Wt2hi + 8192;
    __hip_bfloat16* bfbuf = Wt2lo + 8192;            // N*128 (featbf, then tbf)
    __hip_bfloat16* h1    = bfbuf + (size_t)N * 128; // N*128 (layer-1 output)
    __hip_bfloat16* aux   = h1 + (size_t)N * 128;    // N*128 (build scratch only)
    // CSR-build scratch aliases h1/aux (dead until fused1 writes h1, which
    // runs strictly after the build in stream order):
    //   histA + scanA + blockSums + partial(32.6MB) -> on h1 (43.5MB)
    //   pairs (int[E], 4.8MB)                       -> on aux
    int* histA          = (int*)h1;                  // HISTA_PAD
    int* scanA          = histA + HISTA_PAD;         // SCAN_A_PAD + 4
    int* blockSumsA     = scanA + SCAN_A_PAD + 4;    // 256
    unsigned* partial   = (unsigned*)(blockSumsA + 256);  // DOUT_NSLICE * WORDS_N
    int* pairs          = (int*)aux;                 // E

    // ---- CSR + norms build (no global atomics) ----
    degout_hist_kernel<<<DOUT_NCHUNK * DOUT_NSLICE, 256, 0, stream>>>(src, partial);
    degout_combine_kernel<<<(WORDS_N + 255) / 256, 256, 0, stream>>>(partial, norm_out);
    coarse_hist_kernel<<<NB_A, 256, 0, stream>>>(dst, histA, E);
    scan1_kernel<<<SCAN_A_BLOCKS, 256, 0, stream>>>(histA, scanA, blockSumsA, SCAN_A_N);
    scan2_kernel<<<1, 256, 0, stream>>>(blockSumsA, SCAN_A_BLOCKS);
    scan3_kernel<<<SCAN_A_BLOCKS, 256, 0, stream>>>(scanA, blockSumsA);
    coarse_scatter_kernel<<<NB_A, 256, 0, stream>>>(src, dst, scanA, pairs, E);
    bucket_sort_kernel<<<NCB, 256, 0, stream>>>(pairs, scanA, csr, row_start, norm_in, E);
    f2bf_kernel<<<(N * 16 + 255) / 256, 256, 0, stream>>>(feat, bfbuf, N * 16);
    wsplit_kernel<<<64, 256, 0, stream>>>(W0, 128, Wt0hi, Wt0lo);
    wsplit_kernel<<<64, 256, 0, stream>>>(W1, 128, Wt1hi, Wt1lo);
    wsplit_kernel<<<32, 256, 0, stream>>>(W2, 64, Wt2hi, Wt2lo);

    const int fusedBlocks = (N + 31) / 32;           // 5313
    const int gatherBlocks = (N * 16 + 255) / 256;

    // ---- Layer 1 (fused): h1 = relu(agg(featbf*no)*ni @ W0 + b0) * no
    fused_layer_kernel<true, false><<<fusedBlocks, 256, 0, stream>>>(
        bfbuf, csr, row_start, norm_out, norm_in, Wt0hi, Wt0lo, b0, norm_out,
        nullptr, nullptr, h1);

    // ---- Layers 2+3 (fused): t = relu(agg(h1)*ni @ W1 + b1)*no; tbf = t @ W2
    // tbf overwrites bfbuf (featbf dead after layer 1).
    fused_layer_kernel<false, true><<<fusedBlocks, 256, 0, stream>>>(
        h1, csr, row_start, nullptr, norm_in, Wt1hi, Wt1lo, b1, norm_out,
        Wt2hi, Wt2lo, bfbuf);

    // ---- final: out = agg(tbf)*ni + b2
    gather_kernel<64, false, false, true><<<gatherBlocks, 256, 0, stream>>>(
        bfbuf, csr, row_start, nullptr, norm_in, b2, out, nullptr, nullptr);
}